// Round 4
// baseline (453.449 us; speedup 1.0000x reference)
//
#include <hip/hip_runtime.h>

#define T_TOK 65536
#define BATCH 64
#define XDIM  512
#define HDIM  512
#define YDIM  2560

#define BK 64
#define FTM 32        // fused kernel: tokens per block

#define SB_KC 64      // segbias k-chunk
#define SB_KS 40      // 2560 / 64
#define SB_BG 8       // batches per block

#define PREP_CONV   16384
#define PREP_TRANS  2048
#define PREP_SB     320   // SB_KS * 8

typedef float  f32x4  __attribute__((ext_vector_type(4)));
typedef __bf16 bf16x8 __attribute__((ext_vector_type(8)));

__device__ __forceinline__ unsigned short f2bf(float f) {
    unsigned int u = __float_as_uint(f);
    return (unsigned short)((u + 0x7FFFu + ((u >> 16) & 1u)) >> 16);  // RNE
}

__device__ __forceinline__ float bf2f(unsigned short u) {
    return __uint_as_float((unsigned int)u << 16);
}

__device__ __forceinline__ void load_lds16(const unsigned short* g, unsigned short* l) {
    __builtin_amdgcn_global_load_lds(
        (const __attribute__((address_space(1))) unsigned int*)g,
        (__attribute__((address_space(3))) unsigned int*)l, 16, 0, 0);
}

__device__ __forceinline__ int lower_bound_seg(const int* __restrict__ s, int n, int v) {
    int lo = 0, hi = n;
    while (lo < hi) { int mid = (lo + hi) >> 1; if (s[mid] < v) lo = mid + 1; else hi = mid; }
    return lo;
}

// ---------------- prep: ps->bf16 convert | weight transposes | segbias partials, one grid
__global__ __launch_bounds__(256) void prep_kernel(const float* __restrict__ ps,
                                                   unsigned short* __restrict__ psb,
                                                   const float* __restrict__ W1,
                                                   const float* __restrict__ W2,
                                                   unsigned short* __restrict__ w1t,
                                                   unsigned short* __restrict__ w2t,
                                                   const float* __restrict__ io,
                                                   float* __restrict__ partial) {
    __shared__ float sio[SB_BG][SB_KC];
    const int blk = blockIdx.x;
    const int t = threadIdx.x;

    if (blk < PREP_CONV) {
        size_t idx = (size_t)blk * 256 + t;
        const float4* s4 = reinterpret_cast<const float4*>(ps) + idx * 2;
        float4 a = s4[0], b = s4[1];
        ushort4 o0, o1;
        o0.x = f2bf(a.x); o0.y = f2bf(a.y); o0.z = f2bf(a.z); o0.w = f2bf(a.w);
        o1.x = f2bf(b.x); o1.y = f2bf(b.y); o1.z = f2bf(b.z); o1.w = f2bf(b.w);
        reinterpret_cast<ushort4*>(psb)[idx * 2 + 0] = o0;
        reinterpret_cast<ushort4*>(psb)[idx * 2 + 1] = o1;
    } else if (blk < PREP_CONV + PREP_TRANS) {
        int bb = blk - PREP_CONV;
        const float* src = bb < 1024 ? W1 : W2;
        unsigned short* dst = bb < 1024 ? w1t : w2t;
        int idx = (bb & 1023) * 256 + t;
        int nn = idx >> 9, kk = idx & 511;
        dst[idx] = f2bf(src[(size_t)kk * 512 + nn]);
    } else {
        int sb = blk - PREP_CONV - PREP_TRANS;
        int s = sb >> 3, g = sb & 7;
        for (int i = t; i < SB_BG * SB_KC; i += 256) {
            int bb = i >> 6, kk = i & 63;
            sio[bb][kk] = io[(size_t)(g * SB_BG + bb) * YDIM + s * SB_KC + kk];
        }
        __syncthreads();
        float acc[SB_BG][2] = {};
        const int k0 = 512 + s * SB_KC;
        #pragma unroll 4
        for (int kk = 0; kk < SB_KC; kk++) {
            float wa = W1[(size_t)(k0 + kk) * 512 + t];
            float wb = W1[(size_t)(k0 + kk) * 512 + t + 256];
            #pragma unroll
            for (int bb = 0; bb < SB_BG; bb++) {
                acc[bb][0] += sio[bb][kk] * wa;
                acc[bb][1] += sio[bb][kk] * wb;
            }
        }
        #pragma unroll
        for (int bb = 0; bb < SB_BG; bb++) {
            int b = g * SB_BG + bb;
            partial[((size_t)s * BATCH + b) * 512 + t]       = acc[bb][0];
            partial[((size_t)s * BATCH + b) * 512 + t + 256] = acc[bb][1];
        }
    }
}

// ---------------- segbias[b][n] = sum_s partial[s][b][n]
__global__ __launch_bounds__(256) void segbias_reduce(const float* __restrict__ partial,
                                                      float* __restrict__ segbias) {
    int idx = blockIdx.x * 256 + threadIdx.x;
    float s = 0.f;
    #pragma unroll
    for (int i = 0; i < SB_KS; i++) s += partial[(size_t)i * BATCH * 512 + idx];
    segbias[idx] = s;
}

// XOR-swizzled fragment access: row-granule-stride G8 granules of 8 shorts,
// logical granule c of row R stored at (c ^ (R&7)).
#define FRAG8(sh, R, c)  (*reinterpret_cast<const bf16x8*>(&(sh)[((R) * 8  + (((c) ^ ((R) & 7)))) * 8]))
#define FRAG64(sh, R, c) (*reinterpret_cast<const bf16x8*>(&(sh)[((R) * 64 + (((c) ^ ((R) & 7)))) * 8]))

// ---------------- fused GEMM1+GEMM2: logits = relu(relu(psb@W1u^T + segbias + b1) @ W2^T + b2) . W3
// h1 tile (32x512 bf16) lives entirely in LDS; logits exact per block (no atomics).
__global__ __launch_bounds__(256) void fused_gemm(const unsigned short* __restrict__ psb,
                                                  const unsigned short* __restrict__ w1t,
                                                  const unsigned short* __restrict__ w2t,
                                                  const float* __restrict__ segbias,
                                                  const float* __restrict__ b1,
                                                  const float* __restrict__ b2,
                                                  const float* __restrict__ w3,
                                                  const int* __restrict__ segids,
                                                  float* __restrict__ logits) {
    __shared__ unsigned short h1t[FTM * 512];   // 32 KB, swizzled
    __shared__ unsigned short shA[FTM * BK];    // 4 KB
    __shared__ unsigned short shB[128 * BK];    // 16 KB
    __shared__ float part[FTM][4];

    const int m0 = blockIdx.x * FTM;
    const int t = threadIdx.x;
    const int w = t >> 6, L = t & 63;
    const int lrow = L & 15, lq = L >> 4;
    const int ncol = w * 32;                    // this wave's 32-col slice within each 128-sub

    // ---- phase A: h1[32][512] -> LDS
    for (int ns = 0; ns < 4; ns++) {
        f32x4 acc[2][2] = {};
        for (int kt = 0; kt < XDIM; kt += BK) {
            {   // stage A 32x64: 256 granules, 1/thread
                int r_ = t >> 3, c_ = t & 7, cs_ = c_ ^ (r_ & 7);
                load_lds16(psb + (size_t)(m0 + r_) * XDIM + kt + cs_ * 8, &shA[t * 8]);
            }
            #pragma unroll
            for (int i_ = 0; i_ < 4; i_++) {   // stage B 128x64: 4/thread
                int g_ = i_ * 256 + t;
                int r_ = g_ >> 3, c_ = g_ & 7, cs_ = c_ ^ (r_ & 7);
                load_lds16(w1t + (size_t)(ns * 128 + r_) * HDIM + kt + cs_ * 8, &shB[g_ * 8]);
            }
            __syncthreads();
            #pragma unroll
            for (int ks = 0; ks < BK; ks += 32) {
                bf16x8 af[2], bf[2];
                #pragma unroll
                for (int i = 0; i < 2; i++) af[i] = FRAG8(shA, i * 16 + lrow, (ks >> 3) + lq);
                #pragma unroll
                for (int j = 0; j < 2; j++) bf[j] = FRAG8(shB, ncol + j * 16 + lrow, (ks >> 3) + lq);
                #pragma unroll
                for (int i = 0; i < 2; i++)
                    #pragma unroll
                    for (int j = 0; j < 2; j++)
                        acc[i][j] = __builtin_amdgcn_mfma_f32_16x16x32_bf16(af[i], bf[j], acc[i][j], 0, 0, 0);
            }
            __syncthreads();
        }
        // epilogue: relu + biases -> h1t (swizzled bf16)
        #pragma unroll
        for (int i = 0; i < 2; i++) {
            #pragma unroll
            for (int r = 0; r < 4; r++) {
                int hr = i * 16 + lq * 4 + r;
                int sg = segids[m0 + hr];
                const float* sb = segbias + (size_t)sg * HDIM;
                #pragma unroll
                for (int j = 0; j < 2; j++) {
                    int hc = ns * 128 + ncol + j * 16 + lrow;   // C/D: col=lane&15, row=(lane>>4)*4+r
                    float v = acc[i][j][r] + sb[hc] + b1[hc];
                    v = v > 0.f ? v : 0.f;
                    h1t[hr * 512 + (((hc >> 3) ^ (hr & 7)) * 8) + (hc & 7)] = f2bf(v);
                }
            }
        }
    }
    __syncthreads();   // h1t complete & visible; shA/shB free

    // ---- phase B: logits[m0..m0+32] = relu(h1 @ W2^T + b2) . W3
    float lp[2][4] = {};
    for (int ns2 = 0; ns2 < 4; ns2++) {
        f32x4 acc[2][2] = {};
        for (int kt = 0; kt < HDIM; kt += BK) {
            #pragma unroll
            for (int i_ = 0; i_ < 4; i_++) {   // stage B = w2t rows ns2*128..+128
                int g_ = i_ * 256 + t;
                int r_ = g_ >> 3, c_ = g_ & 7, cs_ = c_ ^ (r_ & 7);
                load_lds16(w2t + (size_t)(ns2 * 128 + r_) * HDIM + kt + cs_ * 8, &shB[g_ * 8]);
            }
            __syncthreads();
            #pragma unroll
            for (int ks = 0; ks < BK; ks += 32) {
                bf16x8 af[2], bf[2];
                #pragma unroll
                for (int i = 0; i < 2; i++) af[i] = FRAG64(h1t, i * 16 + lrow, ((kt + ks) >> 3) + lq);
                #pragma unroll
                for (int j = 0; j < 2; j++) bf[j] = FRAG8(shB, ncol + j * 16 + lrow, (ks >> 3) + lq);
                #pragma unroll
                for (int i = 0; i < 2; i++)
                    #pragma unroll
                    for (int j = 0; j < 2; j++)
                        acc[i][j] = __builtin_amdgcn_mfma_f32_16x16x32_bf16(af[i], bf[j], acc[i][j], 0, 0, 0);
            }
            __syncthreads();
        }
        // epilogue: relu(h2)+dot w3, reduce over this wave's 32 cols
        #pragma unroll
        for (int i = 0; i < 2; i++) {
            #pragma unroll
            for (int r = 0; r < 4; r++) {
                float p = 0.f;
                #pragma unroll
                for (int j = 0; j < 2; j++) {
                    int gn = ns2 * 128 + ncol + j * 16 + lrow;
                    float h2 = acc[i][j][r] + b2[gn];
                    h2 = h2 > 0.f ? h2 : 0.f;
                    p += h2 * w3[gn];
                }
                p += __shfl_xor(p, 1, 64);
                p += __shfl_xor(p, 2, 64);
                p += __shfl_xor(p, 4, 64);
                p += __shfl_xor(p, 8, 64);
                lp[i][r] += p;
            }
        }
    }
    if (lrow == 0) {
        #pragma unroll
        for (int i = 0; i < 2; i++)
            #pragma unroll
            for (int r = 0; r < 4; r++)
                part[i * 16 + lq * 4 + r][w] = lp[i][r];
    }
    __syncthreads();
    if (t < FTM)
        logits[m0 + t] = part[t][0] + part[t][1] + part[t][2] + part[t][3];
}

// ---------------- per-segment softmax stats
__global__ __launch_bounds__(256) void stats_kernel(const float* __restrict__ logits,
                                                    const int* __restrict__ segids,
                                                    float* __restrict__ stats) {
    const int b = blockIdx.x;
    const int t = threadIdx.x;
    __shared__ float sred[4];
    const int start = lower_bound_seg(segids, T_TOK, b);
    const int end   = lower_bound_seg(segids, T_TOK, b + 1);
    float m = -3.4e38f;
    for (int i = start + t; i < end; i += 256) m = fmaxf(m, logits[i]);
    for (int d = 32; d; d >>= 1) m = fmaxf(m, __shfl_down(m, d, 64));
    if ((t & 63) == 0) sred[t >> 6] = m;
    __syncthreads();
    m = fmaxf(fmaxf(sred[0], sred[1]), fmaxf(sred[2], sred[3]));
    __syncthreads();
    float s = 0.f;
    for (int i = start + t; i < end; i += 256) s += __expf(logits[i] - m);
    for (int d = 32; d; d >>= 1) s += __shfl_down(s, d, 64);
    if ((t & 63) == 0) sred[t >> 6] = s;
    __syncthreads();
    if (t == 0) { stats[2 * b] = m; stats[2 * b + 1] = sred[0] + sred[1] + sred[2] + sred[3]; }
}

// ---------------- pooled[b][c] += sum_t w[t] * psb[t][c]
__global__ __launch_bounds__(512) void pool_kernel(const unsigned short* __restrict__ psb,
                                                   const float* __restrict__ logits,
                                                   const int* __restrict__ segids,
                                                   const float* __restrict__ stats,
                                                   float* __restrict__ pooled) {
    const int s = blockIdx.x;       // 0..15 split
    const int b = blockIdx.y;
    const int t = threadIdx.x;
    __shared__ float wv[512];
    const int start = lower_bound_seg(segids, T_TOK, b);
    const int end   = lower_bound_seg(segids, T_TOK, b + 1);
    const int n = end - start;
    const int per = (n + 15) >> 4;
    const int s0 = start + s * per;
    const int s1 = min(s0 + per, end);
    const float m = stats[2 * b];
    const float inv = 1.f / stats[2 * b + 1];
    float acc = 0.f;
    for (int base = s0; base < s1; base += 512) {
        int cnt = min(512, s1 - base);
        __syncthreads();
        if (t < cnt) wv[t] = __expf(logits[base + t] - m) * inv;
        __syncthreads();
        for (int i = 0; i < cnt; i++)
            acc += wv[i] * bf2f(psb[(size_t)(base + i) * XDIM + t]);
    }
    if (s1 > s0) atomicAdd(&pooled[b * XDIM + t], acc);
}

// ---------------- final_fc
__global__ __launch_bounds__(512) void final_kernel(const float* __restrict__ pooled,
                                                    const float* __restrict__ wf1,
                                                    const float* __restrict__ bf1,
                                                    const float* __restrict__ wf2,
                                                    const float* __restrict__ bf2,
                                                    float* __restrict__ out) {
    const int b = blockIdx.x;
    const int t = threadIdx.x;
    __shared__ float sp[512];
    __shared__ float r0s[8], r1s[8];
    sp[t] = pooled[b * XDIM + t];
    __syncthreads();
    float acc = bf1[t];
    #pragma unroll 4
    for (int k = 0; k < 512; k++) acc += sp[k] * wf1[(size_t)k * 512 + t];
    float h = fmaxf(acc, 0.f);
    float p0 = h * wf2[t * 2 + 0];
    float p1 = h * wf2[t * 2 + 1];
    for (int d = 32; d; d >>= 1) { p0 += __shfl_down(p0, d, 64); p1 += __shfl_down(p1, d, 64); }
    if ((t & 63) == 0) { r0s[t >> 6] = p0; r1s[t >> 6] = p1; }
    __syncthreads();
    if (t == 0) {
        float a = 0.f, c = 0.f;
        #pragma unroll
        for (int i = 0; i < 8; i++) { a += r0s[i]; c += r1s[i]; }
        out[b * 2 + 0] = a + bf2[0];
        out[b * 2 + 1] = c + bf2[1];
    }
}

extern "C" void kernel_launch(void* const* d_in, const int* in_sizes, int n_in,
                              void* d_out, int out_size, void* d_ws, size_t ws_size,
                              hipStream_t stream) {
    const float* ps  = (const float*)d_in[0];
    const float* io  = (const float*)d_in[1];
    const int*   seg = (const int*)d_in[2];
    const float* W1  = (const float*)d_in[3];
    const float* b1  = (const float*)d_in[4];
    const float* W2  = (const float*)d_in[5];
    const float* b2  = (const float*)d_in[6];
    const float* W3  = (const float*)d_in[7];
    // d_in[8] = b3: cancels in segment softmax
    const float* Wf1 = (const float*)d_in[9];
    const float* bf1 = (const float*)d_in[10];
    const float* Wf2 = (const float*)d_in[11];
    const float* bf2 = (const float*)d_in[12];
    float* out = (float*)d_out;

    char* ws = (char*)d_ws;
    float*          segbias = (float*)(ws + 0);                 // 128 KiB
    float*          logits  = (float*)(ws + 131072);            // 256 KiB (written fully, no memset)
    float*          stats   = (float*)(ws + 393216);            // 4 KiB
    float*          pooled  = (float*)(ws + 397312);            // 128 KiB
    unsigned short* w1t     = (unsigned short*)(ws + 528384);   // 512 KiB
    unsigned short* w2t     = (unsigned short*)(ws + 1052672);  // 512 KiB
    float*          partial = (float*)(ws + 1576960);           // 5.25 MiB
    unsigned short* psb     = (unsigned short*)(ws + 8388608);  // 64 MiB

    hipMemsetAsync(ws + 397312, 0, 131072, stream);   // pooled only

    prep_kernel<<<PREP_CONV + PREP_TRANS + PREP_SB, 256, 0, stream>>>(
        ps, psb, W1, W2, w1t, w2t, io, partial);
    segbias_reduce<<<128, 256, 0, stream>>>(partial, segbias);
    fused_gemm<<<T_TOK / FTM, 256, 0, stream>>>(psb, w1t, w2t, segbias, b1, b2, W3, seg, logits);
    stats_kernel<<<64, 256, 0, stream>>>(logits, seg, stats);
    pool_kernel<<<dim3(16, 64), 512, 0, stream>>>(psb, logits, seg, stats, pooled);
    final_kernel<<<64, 512, 0, stream>>>(pooled, Wf1, bf1, Wf2, bf2, out);
}

// Round 5
// 391.667 us; speedup vs baseline: 1.1577x; 1.1577x over previous
//
#include <hip/hip_runtime.h>

#define T_TOK 65536
#define BATCH 64
#define XDIM  512
#define HDIM  512
#define YDIM  2560

#define BK 64
#define GM_TM 256     // gemm m-tile
#define GM_TN 128     // gemm n-tile

#define SB_KC 64      // segbias k-chunk
#define SB_KS 40      // 2560 / 64
#define SB_BG 8       // batches per block

#define PREP_CONV   16384
#define PREP_TRANS  2048
#define PREP_SB     320   // SB_KS * 8

typedef float  f32x4  __attribute__((ext_vector_type(4)));
typedef __bf16 bf16x8 __attribute__((ext_vector_type(8)));

__device__ __forceinline__ unsigned short f2bf(float f) {
    unsigned int u = __float_as_uint(f);
    return (unsigned short)((u + 0x7FFFu + ((u >> 16) & 1u)) >> 16);  // RNE
}

__device__ __forceinline__ float bf2f(unsigned short u) {
    return __uint_as_float((unsigned int)u << 16);
}

__device__ __forceinline__ void load_lds16(const unsigned short* g, unsigned short* l) {
    __builtin_amdgcn_global_load_lds(
        (const __attribute__((address_space(1))) unsigned int*)g,
        (__attribute__((address_space(3))) unsigned int*)l, 16, 0, 0);
}

__device__ __forceinline__ int lower_bound_seg(const int* __restrict__ s, int n, int v) {
    int lo = 0, hi = n;
    while (lo < hi) { int mid = (lo + hi) >> 1; if (s[mid] < v) lo = mid + 1; else hi = mid; }
    return lo;
}

// ---------------- prep: ps->bf16 convert | weight transposes | segbias partials, one grid
__global__ __launch_bounds__(256) void prep_kernel(const float* __restrict__ ps,
                                                   unsigned short* __restrict__ psb,
                                                   const float* __restrict__ W1,
                                                   const float* __restrict__ W2,
                                                   unsigned short* __restrict__ w1t,
                                                   unsigned short* __restrict__ w2t,
                                                   const float* __restrict__ io,
                                                   float* __restrict__ partial) {
    __shared__ float sio[SB_BG][SB_KC];
    const int blk = blockIdx.x;
    const int t = threadIdx.x;

    if (blk < PREP_CONV) {
        size_t idx = (size_t)blk * 256 + t;
        const float4* s4 = reinterpret_cast<const float4*>(ps) + idx * 2;
        float4 a = s4[0], b = s4[1];
        ushort4 o0, o1;
        o0.x = f2bf(a.x); o0.y = f2bf(a.y); o0.z = f2bf(a.z); o0.w = f2bf(a.w);
        o1.x = f2bf(b.x); o1.y = f2bf(b.y); o1.z = f2bf(b.z); o1.w = f2bf(b.w);
        reinterpret_cast<ushort4*>(psb)[idx * 2 + 0] = o0;
        reinterpret_cast<ushort4*>(psb)[idx * 2 + 1] = o1;
    } else if (blk < PREP_CONV + PREP_TRANS) {
        int bb = blk - PREP_CONV;
        const float* src = bb < 1024 ? W1 : W2;
        unsigned short* dst = bb < 1024 ? w1t : w2t;
        int idx = (bb & 1023) * 256 + t;
        int nn = idx >> 9, kk = idx & 511;
        dst[idx] = f2bf(src[(size_t)kk * 512 + nn]);
    } else {
        int sb = blk - PREP_CONV - PREP_TRANS;
        int s = sb >> 3, g = sb & 7;
        for (int i = t; i < SB_BG * SB_KC; i += 256) {
            int bb = i >> 6, kk = i & 63;
            sio[bb][kk] = io[(size_t)(g * SB_BG + bb) * YDIM + s * SB_KC + kk];
        }
        __syncthreads();
        float acc[SB_BG][2] = {};
        const int k0 = 512 + s * SB_KC;
        #pragma unroll 4
        for (int kk = 0; kk < SB_KC; kk++) {
            float wa = W1[(size_t)(k0 + kk) * 512 + t];
            float wb = W1[(size_t)(k0 + kk) * 512 + t + 256];
            #pragma unroll
            for (int bb = 0; bb < SB_BG; bb++) {
                acc[bb][0] += sio[bb][kk] * wa;
                acc[bb][1] += sio[bb][kk] * wb;
            }
        }
        #pragma unroll
        for (int bb = 0; bb < SB_BG; bb++) {
            int b = g * SB_BG + bb;
            partial[((size_t)s * BATCH + b) * 512 + t]       = acc[bb][0];
            partial[((size_t)s * BATCH + b) * 512 + t + 256] = acc[bb][1];
        }
    }
}

// ---------------- segbias[b][n] = sum_s partial[s][b][n]
__global__ __launch_bounds__(256) void segbias_reduce(const float* __restrict__ partial,
                                                      float* __restrict__ segbias) {
    int idx = blockIdx.x * 256 + threadIdx.x;
    float s = 0.f;
    #pragma unroll
    for (int i = 0; i < SB_KS; i++) s += partial[(size_t)i * BATCH * 512 + idx];
    segbias[idx] = s;
}

// XOR-swizzled tile: granule stride 8/row; logical granule c of row R at (c ^ (R&7)).
// Swizzle applied at the GLOBAL source address (glds forces lane-linear LDS layout).
#define FRAG_AT(sh, R, c) (*reinterpret_cast<const bf16x8*>(&(sh)[((R) * 8 + (((c) ^ ((R) & 7)))) * 8]))

// ---------------- GEMM1: h1 = relu(psb @ W1u^T + segbias[seg] + b1), bf16 out
// 256x128 tile, 8 waves of 64x64 (8 ds_read : 16 MFMA per ks32 = 32 FLOP/LDS-byte edge)
__global__ __launch_bounds__(512) void gemm1_kernel(const unsigned short* __restrict__ psb,
                                                    const unsigned short* __restrict__ w1t,
                                                    const float* __restrict__ segbias,
                                                    const float* __restrict__ b1,
                                                    const int* __restrict__ segids,
                                                    unsigned short* __restrict__ h1) {
    __shared__ unsigned short shA[GM_TM * BK];   // 32 KB
    __shared__ unsigned short shB[GM_TN * BK];   // 16 KB -> 48 KB total, 3 blocks/CU

    const int bid = blockIdx.x;
    const int xcd = bid & 7;
    const int j = bid >> 3;
    const int n0 = (j & 3) * GM_TN;
    const int m0 = ((j >> 2) * 8 + xcd) * GM_TM;   // 4 n-blocks of one m-tile share an XCD
    const int t = threadIdx.x;
    const int w = t >> 6, L = t & 63;
    const int mbase = (w >> 1) * 64, nbase = (w & 1) * 64;
    const int lrow = L & 15, lq = L >> 4;

    f32x4 acc[4][4] = {};

    for (int kt = 0; kt < XDIM; kt += BK) {
        #pragma unroll
        for (int i_ = 0; i_ < 4; i_++) {   // A: 256x64, 2048 granules, 4/thread
            int g_ = i_ * 512 + t;
            int r_ = g_ >> 3, c_ = g_ & 7, cs_ = c_ ^ (r_ & 7);
            load_lds16(psb + (size_t)(m0 + r_) * XDIM + kt + cs_ * 8, &shA[g_ * 8]);
        }
        #pragma unroll
        for (int i_ = 0; i_ < 2; i_++) {   // B: 128x64, 1024 granules, 2/thread
            int g_ = i_ * 512 + t;
            int r_ = g_ >> 3, c_ = g_ & 7, cs_ = c_ ^ (r_ & 7);
            load_lds16(w1t + (size_t)(n0 + r_) * HDIM + kt + cs_ * 8, &shB[g_ * 8]);
        }
        __syncthreads();
        #pragma unroll
        for (int ks = 0; ks < BK; ks += 32) {
            bf16x8 af[4], bfr[4];
            #pragma unroll
            for (int i = 0; i < 4; i++) af[i] = FRAG_AT(shA, mbase + i * 16 + lrow, (ks >> 3) + lq);
            #pragma unroll
            for (int jj = 0; jj < 4; jj++) bfr[jj] = FRAG_AT(shB, nbase + jj * 16 + lrow, (ks >> 3) + lq);
            #pragma unroll
            for (int i = 0; i < 4; i++)
                #pragma unroll
                for (int jj = 0; jj < 4; jj++)
                    acc[i][jj] = __builtin_amdgcn_mfma_f32_16x16x32_bf16(af[i], bfr[jj], acc[i][jj], 0, 0, 0);
        }
        __syncthreads();
    }

    #pragma unroll
    for (int i = 0; i < 4; i++) {
        #pragma unroll
        for (int r = 0; r < 4; r++) {
            int gm = m0 + mbase + i * 16 + lq * 4 + r;
            int sg = segids[gm];
            const float* sb = segbias + (size_t)sg * HDIM;
            #pragma unroll
            for (int jj = 0; jj < 4; jj++) {
                int gn = n0 + nbase + jj * 16 + lrow;   // C/D: col=lane&15, row=(lane>>4)*4+r
                float v = acc[i][jj][r] + sb[gn] + b1[gn];
                v = v > 0.f ? v : 0.f;
                h1[(size_t)gm * HDIM + gn] = f2bf(v);
            }
        }
    }
}

// ---------------- GEMM2 fused: logits8[slice] = partial of relu(h1 @ W2^T + b2) . W3
// plain stores into 8 disjoint slices (by n-block and wave n-half): no atomics, no memset.
__global__ __launch_bounds__(512) void gemm2_kernel(const unsigned short* __restrict__ h1,
                                                    const unsigned short* __restrict__ w2t,
                                                    const float* __restrict__ b2,
                                                    const float* __restrict__ w3,
                                                    float* __restrict__ logits8) {
    __shared__ unsigned short shA[GM_TM * BK];
    __shared__ unsigned short shB[GM_TN * BK];

    const int bid = blockIdx.x;
    const int xcd = bid & 7;
    const int j = bid >> 3;
    const int n0 = (j & 3) * GM_TN;
    const int m0 = ((j >> 2) * 8 + xcd) * GM_TM;
    const int t = threadIdx.x;
    const int w = t >> 6, L = t & 63;
    const int mbase = (w >> 1) * 64, nbase = (w & 1) * 64;
    const int lrow = L & 15, lq = L >> 4;

    f32x4 acc[4][4] = {};

    for (int kt = 0; kt < HDIM; kt += BK) {
        #pragma unroll
        for (int i_ = 0; i_ < 4; i_++) {
            int g_ = i_ * 512 + t;
            int r_ = g_ >> 3, c_ = g_ & 7, cs_ = c_ ^ (r_ & 7);
            load_lds16(h1 + (size_t)(m0 + r_) * HDIM + kt + cs_ * 8, &shA[g_ * 8]);
        }
        #pragma unroll
        for (int i_ = 0; i_ < 2; i_++) {
            int g_ = i_ * 512 + t;
            int r_ = g_ >> 3, c_ = g_ & 7, cs_ = c_ ^ (r_ & 7);
            load_lds16(w2t + (size_t)(n0 + r_) * HDIM + kt + cs_ * 8, &shB[g_ * 8]);
        }
        __syncthreads();
        #pragma unroll
        for (int ks = 0; ks < BK; ks += 32) {
            bf16x8 af[4], bfr[4];
            #pragma unroll
            for (int i = 0; i < 4; i++) af[i] = FRAG_AT(shA, mbase + i * 16 + lrow, (ks >> 3) + lq);
            #pragma unroll
            for (int jj = 0; jj < 4; jj++) bfr[jj] = FRAG_AT(shB, nbase + jj * 16 + lrow, (ks >> 3) + lq);
            #pragma unroll
            for (int i = 0; i < 4; i++)
                #pragma unroll
                for (int jj = 0; jj < 4; jj++)
                    acc[i][jj] = __builtin_amdgcn_mfma_f32_16x16x32_bf16(af[i], bfr[jj], acc[i][jj], 0, 0, 0);
        }
        __syncthreads();
    }

    float w3v[4], b2v[4];
    #pragma unroll
    for (int jj = 0; jj < 4; jj++) {
        int gn = n0 + nbase + jj * 16 + lrow;
        w3v[jj] = w3[gn];
        b2v[jj] = b2[gn];
    }
    const int slice = (j & 3) * 2 + (w & 1);   // 8 disjoint 64-col slices of the n dim
    #pragma unroll
    for (int i = 0; i < 4; i++) {
        #pragma unroll
        for (int r = 0; r < 4; r++) {
            float p = 0.f;
            #pragma unroll
            for (int jj = 0; jj < 4; jj++) {
                float h2 = acc[i][jj][r] + b2v[jj];
                h2 = h2 > 0.f ? h2 : 0.f;
                p += h2 * w3v[jj];
            }
            p += __shfl_xor(p, 1, 64);
            p += __shfl_xor(p, 2, 64);
            p += __shfl_xor(p, 4, 64);
            p += __shfl_xor(p, 8, 64);
            if (lrow == 0)
                logits8[(size_t)slice * T_TOK + m0 + mbase + i * 16 + lq * 4 + r] = p;
        }
    }
}

// ---------------- logits = sum of 8 slices; then per-segment softmax stats
__global__ __launch_bounds__(256) void stats_kernel(const float* __restrict__ logits8,
                                                    float* __restrict__ logits,
                                                    const int* __restrict__ segids,
                                                    float* __restrict__ stats) {
    const int b = blockIdx.x;
    const int t = threadIdx.x;
    __shared__ float sred[4];
    const int start = lower_bound_seg(segids, T_TOK, b);
    const int end   = lower_bound_seg(segids, T_TOK, b + 1);
    float m = -3.4e38f;
    for (int i = start + t; i < end; i += 256) {
        float l = 0.f;
        #pragma unroll
        for (int s = 0; s < 8; s++) l += logits8[(size_t)s * T_TOK + i];
        logits[i] = l;
        m = fmaxf(m, l);
    }
    for (int d = 32; d; d >>= 1) m = fmaxf(m, __shfl_down(m, d, 64));
    if ((t & 63) == 0) sred[t >> 6] = m;
    __syncthreads();
    m = fmaxf(fmaxf(sred[0], sred[1]), fmaxf(sred[2], sred[3]));
    __syncthreads();
    float s = 0.f;
    for (int i = start + t; i < end; i += 256) s += __expf(logits[i] - m);
    for (int d = 32; d; d >>= 1) s += __shfl_down(s, d, 64);
    if ((t & 63) == 0) sred[t >> 6] = s;
    __syncthreads();
    if (t == 0) { stats[2 * b] = m; stats[2 * b + 1] = sred[0] + sred[1] + sred[2] + sred[3]; }
}

// ---------------- pooled[b][c] += sum_t w[t] * psb[t][c]
__global__ __launch_bounds__(512) void pool_kernel(const unsigned short* __restrict__ psb,
                                                   const float* __restrict__ logits,
                                                   const int* __restrict__ segids,
                                                   const float* __restrict__ stats,
                                                   float* __restrict__ pooled) {
    const int s = blockIdx.x;       // 0..15 split
    const int b = blockIdx.y;
    const int t = threadIdx.x;
    __shared__ float wv[512];
    const int start = lower_bound_seg(segids, T_TOK, b);
    const int end   = lower_bound_seg(segids, T_TOK, b + 1);
    const int n = end - start;
    const int per = (n + 15) >> 4;
    const int s0 = start + s * per;
    const int s1 = min(s0 + per, end);
    const float m = stats[2 * b];
    const float inv = 1.f / stats[2 * b + 1];
    float acc = 0.f;
    for (int base = s0; base < s1; base += 512) {
        int cnt = min(512, s1 - base);
        __syncthreads();
        if (t < cnt) wv[t] = __expf(logits[base + t] - m) * inv;
        __syncthreads();
        for (int i = 0; i < cnt; i++)
            acc += wv[i] * bf2f(psb[(size_t)(base + i) * XDIM + t]);
    }
    if (s1 > s0) atomicAdd(&pooled[b * XDIM + t], acc);
}

// ---------------- final_fc
__global__ __launch_bounds__(512) void final_kernel(const float* __restrict__ pooled,
                                                    const float* __restrict__ wf1,
                                                    const float* __restrict__ bf1,
                                                    const float* __restrict__ wf2,
                                                    const float* __restrict__ bf2,
                                                    float* __restrict__ out) {
    const int b = blockIdx.x;
    const int t = threadIdx.x;
    __shared__ float sp[512];
    __shared__ float r0s[8], r1s[8];
    sp[t] = pooled[b * XDIM + t];
    __syncthreads();
    float acc = bf1[t];
    #pragma unroll 4
    for (int k = 0; k < 512; k++) acc += sp[k] * wf1[(size_t)k * 512 + t];
    float h = fmaxf(acc, 0.f);
    float p0 = h * wf2[t * 2 + 0];
    float p1 = h * wf2[t * 2 + 1];
    for (int d = 32; d; d >>= 1) { p0 += __shfl_down(p0, d, 64); p1 += __shfl_down(p1, d, 64); }
    if ((t & 63) == 0) { r0s[t >> 6] = p0; r1s[t >> 6] = p1; }
    __syncthreads();
    if (t == 0) {
        float a = 0.f, c = 0.f;
        #pragma unroll
        for (int i = 0; i < 8; i++) { a += r0s[i]; c += r1s[i]; }
        out[b * 2 + 0] = a + bf2[0];
        out[b * 2 + 1] = c + bf2[1];
    }
}

extern "C" void kernel_launch(void* const* d_in, const int* in_sizes, int n_in,
                              void* d_out, int out_size, void* d_ws, size_t ws_size,
                              hipStream_t stream) {
    const float* ps  = (const float*)d_in[0];
    const float* io  = (const float*)d_in[1];
    const int*   seg = (const int*)d_in[2];
    const float* W1  = (const float*)d_in[3];
    const float* b1  = (const float*)d_in[4];
    const float* W2  = (const float*)d_in[5];
    const float* b2  = (const float*)d_in[6];
    const float* W3  = (const float*)d_in[7];
    // d_in[8] = b3: cancels in segment softmax
    const float* Wf1 = (const float*)d_in[9];
    const float* bf1 = (const float*)d_in[10];
    const float* Wf2 = (const float*)d_in[11];
    const float* bf2 = (const float*)d_in[12];
    float* out = (float*)d_out;

    char* ws = (char*)d_ws;
    float*          segbias = (float*)(ws + 0);                 // 128 KiB
    float*          logits  = (float*)(ws + 131072);            // 256 KiB (fully written by stats)
    float*          stats   = (float*)(ws + 393216);            // 4 KiB
    float*          pooled  = (float*)(ws + 397312);            // 128 KiB
    unsigned short* w1t     = (unsigned short*)(ws + 528384);   // 512 KiB
    unsigned short* w2t     = (unsigned short*)(ws + 1052672);  // 512 KiB
    float*          logits8 = (float*)(ws + 1576960);           // 2 MiB (fully written by gemm2)
    float*          partial = (float*)(ws + 3674112);           // 5.25 MiB
    unsigned short* psb     = (unsigned short*)(ws + 16777216); // 64 MiB
    unsigned short* h1      = (unsigned short*)(ws + 83886080); // 64 MiB

    hipMemsetAsync(ws + 397312, 0, 131072, stream);   // pooled only

    prep_kernel<<<PREP_CONV + PREP_TRANS + PREP_SB, 256, 0, stream>>>(
        ps, psb, W1, W2, w1t, w2t, io, partial);
    segbias_reduce<<<128, 256, 0, stream>>>(partial, segbias);
    gemm1_kernel<<<(T_TOK / GM_TM) * 4, 512, 0, stream>>>(psb, w1t, segbias, b1, seg, h1);
    gemm2_kernel<<<(T_TOK / GM_TM) * 4, 512, 0, stream>>>(h1, w2t, b2, W3, logits8);
    stats_kernel<<<64, 256, 0, stream>>>(logits8, logits, seg, stats);
    pool_kernel<<<dim3(16, 64), 512, 0, stream>>>(psb, logits, seg, stats, pooled);
    final_kernel<<<64, 512, 0, stream>>>(pooled, Wf1, bf1, Wf2, bf2, out);
}